// Round 13
// baseline (556.323 us; speedup 1.0000x reference)
//
#include <hip/hip_runtime.h>

// VQ-VAE quantizer: x [B=32, C=64, T=4096] f32, emb [K=1024, D=64] f32.
// Outputs flat f32: quant_out [B*C*T], codebook_loss [1], commitment_loss [1],
// idx [B*T] (as float).
//
// CORRECTNESS MODEL (validated R2..R9): checker recomputes the reference with
// numpy f32. d_np(k) = RN( fl(S+e2[k]) - 2*g_k ), g_k = sequential-k single-acc
// FMA chain (BLAS). d~64 -> grid ulp(64)=7.6e-6; near-ties decided by numpy's
// exact rounding. Screen: split-bf16 MFMA (x=xh+xl, e=eh+el; xh*eh + xh*el +
// xl*eh, f32 acc) -> |dot~ - g_k| <= ~1.5e-6. Scan u_k = fl(fl(S+e2[k])-2dot~)
// with np-exact fl(S+e2[k]). Certify winner iff v2-v1 > BAND (4e-5); else
// np-exact full rescan (packed-u64 (flip(d)<<10|k) min = value order +
// first-index tie-break). S,e2: numpy pairwise_sum of fl(v*v), n=64
// (8 accs stride-8, ((r0+r1)+(r2+r3))+((r4+r5)+(r6+r7))).
// DO NOT change fallback chain arithmetic/order or S/e2 pairwise pattern.
//
// Perf history: R15 bench 192 (main 124.5); R21 bench 188.7 (BEST, K-split
// 8-wave); R22 193.6. REFUTED levers (busy-times conserved ~21us MFMA /
// ~45us VALU in all 8 variants): reg pipeline depth 2/3 (R17/18/19 --
// allocator hard-caps 64 VGPR, sched sinks or spills), LDS-DMA depth (R20),
// L2 traffic cut 4x (R20/R22), wave doubling (R21 neutral-to-slightly-
// better), barrier cadences. Direct-from-L2 depth-1 (R15/R21) wins.
// R14/R16: uncoalesced per-lane L2 reads are request-rate poison.
// Fixed ~65us of bench total is harness overhead (R16 removed a dispatch,
// total unchanged) -- main is the only addressable budget.
// R23: R21 verbatim + staging parallelized 4x (R21 staged with threads
// 0-127 only -> 6 of 8 waves idle ~7us). 4 threads/row: thread (r,hq) owns
// dims {2hq,2hq+1}, i ascending (per-column chains unchanged); S tree split
// at its internal nodes via pbuf[4][128]: a01,a23,a45,a67 per-thread, then
// S = fl(fl(a01+a23)+fl(a45+a67)) -- bit-identical. LDS 38.4K -> ~40.4K,
// still <= 40960 (4 blocks/CU preserved). Barrier count unchanged.

typedef unsigned long long u64;
typedef unsigned short u16;
typedef __attribute__((ext_vector_type(8))) short bf8_t;   // 8 bf16 (A/B frag)
typedef __attribute__((ext_vector_type(4))) float f4_t;    // 4 f32  (C/D frag)

#define KCB 1024
#define DD 64
#define BB 32
#define TT 4096
#define BT (BB * TT)
#define NELEM (BB * DD * TT)

#define RPB 128                // rows per block
#define NTHR 512               // 8 waves: 4 row-pair owners x 2 K-halves
#define NT 16                  // emb tiles (64 cands each)
#define FB_MAX 48
#define NSL 6                  // FB slots per wave: 8 waves * 6 = 48
#define BAND 4e-5f

#define WS_LOSS 0
#define WS_E2 64
#define WS_EH 2048             // float offset: eh frag table (64Ki u16 = 128KB)
#define WS_EL 34816            // el frag table

static __device__ __forceinline__ u16 bf16rte(float f) {
    unsigned u = __float_as_uint(f);
    return (u16)((u + 0x7FFFu + ((u >> 16) & 1u)) >> 16);
}
static __device__ __forceinline__ unsigned flipf(float f) {
    unsigned u = __float_as_uint(f);
    return (u & 0x80000000u) ? ~u : (u | 0x80000000u);
}
// frag-order index within a 64-cand tile: cand n, dim d -> u16 index
static __device__ __forceinline__ int fragidx(int n, int d) {
    return 1024 * (n >> 4) + 512 * (d >> 5) + 128 * ((d >> 3) & 3)
         + 8 * (n & 15) + (d & 7);
}

// Prep: parallel (256 blocks x 256 thr; block owns 4 cands). np-exact e2 via
// LDS pairwise; split-bf16 frag-order tables; coalesced loads. UNCHANGED.
__global__ void vq_prep(const float* __restrict__ emb, float* __restrict__ ws) {
#pragma clang fp contract(off)
    const int tid = threadIdx.x;
    const int kl = tid >> 6, d = tid & 63;
    const int k = blockIdx.x * 4 + kl;
    if (blockIdx.x == 0 && tid == 0) ws[WS_LOSS] = 0.0f;
    __shared__ float sq[4][64];
    __shared__ float rsh[4][8];
    float v = emb[(size_t)k * DD + d];
    u16 hb = bf16rte(v);
    float hv = __uint_as_float((unsigned)hb << 16);
    u16 lb = bf16rte(v - hv);                  // v-hv exact (Sterbenz)
    u16* ehg = (u16*)(ws + WS_EH) + 4096 * (k >> 6);
    u16* elg = (u16*)(ws + WS_EL) + 4096 * (k >> 6);
    const int ia = fragidx(k & 63, d);
    ehg[ia] = hb; elg[ia] = lb;
    sq[kl][d] = v * v;                         // fl(e*e) individually rounded
    __syncthreads();
    if (tid < 32) {
        const int g = tid >> 3, j = tid & 7;
        float r = sq[g][j];
#pragma unroll
        for (int i = 1; i < 8; ++i) r += sq[g][8 * i + j];   // i ascending
        rsh[g][j] = r;
    }
    __syncthreads();
    if (tid < 4) {
        const float* r = rsh[tid];
        ws[WS_E2 + blockIdx.x * 4 + tid] =
            ((r[0] + r[1]) + (r[2] + r[3])) + ((r[4] + r[5]) + (r[6] + r[7]));
    }
}

__launch_bounds__(NTHR, 4)
__global__ void vq_main(const float* __restrict__ x, const float* __restrict__ emb,
                        float* __restrict__ out, float* __restrict__ ws) {
#pragma clang fp contract(off)
    const int tid = threadIdx.x;
    const int lane = tid & 63;
    const int w = __builtin_amdgcn_readfirstlane(tid >> 6);   // 0..7
    const int w4 = w & 3;                       // row-pair owner
    const int h = w >> 2;                       // K-half: 0 -> it 0..31, 1 -> 32..63
    const int l15 = lane & 15, q = lane >> 4;

    const int row0 = blockIdx.x * RPB;          // 128 | 4096 -> b uniform
    const int b = row0 >> 12;
    const int t0 = row0 & (TT - 1);

    // Arena: [stage] xhT 16K + xlT 16K -> [merge] mv1/mv2/mkf (1.5KB) ->
    // [fallback] efs (16640B) + xfb (48x65 f32). Lifetimes barrier-separated.
    __shared__ __align__(16) char arena[32768];
    u16* xhT = (u16*)arena;
    u16* xlT = (u16*)(arena + 16384);
    float* mv1 = (float*)arena;                 // [128] half-1 v1
    float* mv2 = (float*)(arena + 512);         // [128] half-1 v2
    float* mkf = (float*)(arena + 1024);        // [128] half-1 kf
    float* efs = (float*)arena;
    float* xfb = (float*)(arena + 16640);

    __shared__ float e2l[KCB];                  // np-exact e2, 4KB
    __shared__ float Srow[RPB];
    __shared__ float pbuf[4][RPB];              // S tree partials, 2KB
    __shared__ int kwin[RPB];
    __shared__ int fbrows[FB_MAX];
    __shared__ int fbcnt;
    __shared__ float bsum;

    if (tid == 0) { fbcnt = 0; bsum = 0.0f; }
#pragma unroll
    for (int i = tid; i < KCB; i += NTHR) e2l[i] = ws[WS_E2 + i];

    // x stage: ALL 512 threads, 4 per row. Thread (r_, hq) owns dims
    // {2hq, 2hq+1}, i ascending -- per-column sequential chains identical to
    // champion. Frag writes: same values, same addresses. S pairwise tree
    // split at internal nodes: a01 (hq0), a23 (hq1), a45 (hq2), a67 (hq3);
    // S = fl(fl(a01+a23)+fl(a45+a67)) == ((r0+r1)+(r2+r3))+((r4+r5)+(r6+r7)).
    const int r_ = tid & 127, hq = tid >> 7;
    {
        const float* xr = x + (size_t)b * DD * TT + t0 + r_;
        const int gb = 1024 * (r_ >> 4);
        float rA = 0.0f, rB = 0.0f;
#pragma unroll
        for (int i = 0; i < 64; i += 8) {
#pragma unroll
            for (int jj = 0; jj < 2; ++jj) {
                const int j = 2 * hq + jj;
                float v = xr[(size_t)(i + j) * TT];
                float sqv = v * v;
                if (jj == 0) { if (i == 0) rA = sqv; else rA += sqv; }
                else         { if (i == 0) rB = sqv; else rB += sqv; }
                u16 hb = bf16rte(v);
                float hv = __uint_as_float((unsigned)hb << 16);
                u16 lb = bf16rte(v - hv);      // exact (Sterbenz)
                const int ia = gb + fragidx(r_ & 15, i + j);
                xhT[ia] = hb; xlT[ia] = lb;
            }
        }
        pbuf[hq][r_] = rA + rB;                // internal tree node fl(rA+rB)
    }
    __syncthreads();                           // frags + partials complete

    // A-frags: wave w owns row-groups 2*w4, 2*w4+1 (32 rows); loaded once
    // as whole bf8_t (ds_read_b128 -- codegen invariant, R13 lesson).
    bf8_t ah[2][2], al[2][2];
#pragma unroll
    for (int g = 0; g < 2; ++g) {
        const int gg = 2 * w4 + g;
        ah[g][0] = *(const bf8_t*)&xhT[1024 * gg + 8 * lane];
        ah[g][1] = *(const bf8_t*)&xhT[1024 * gg + 512 + 8 * lane];
        al[g][0] = *(const bf8_t*)&xlT[1024 * gg + 8 * lane];
        al[g][1] = *(const bf8_t*)&xlT[1024 * gg + 512 + 8 * lane];
    }
    if (tid < RPB)                             // Srow combine (tree root)
        Srow[tid] = (pbuf[0][tid] + pbuf[1][tid]) + (pbuf[2][tid] + pbuf[3][tid]);
    __syncthreads();                           // Srow ready; arena reads done

    float Sv[8];
#pragma unroll
    for (int g = 0; g < 2; ++g)
#pragma unroll
        for (int rg = 0; rg < 4; ++rg)
            Sv[4 * g + rg] = Srow[32 * w4 + 16 * g + 4 * q + rg];

    // In-register scan state: thread owns 8 rows (4q+rg in each group), cols
    // congruent to l15 (mod 16). All indices compile-time after unroll.
    float v1[8], v2[8], kf[8];
#pragma unroll
    for (int s = 0; s < 8; ++s) { v1[s] = 3.4e38f; v2[s] = 3.4e38f; kf[s] = 0.0f; }

    const u16* ehg = (const u16*)(ws + WS_EH);
    const u16* elg = (const u16*)(ws + WS_EL);

    // One K-step: 12 MFMA + scan for 16 candidates. Arithmetic identical to
    // R10/R15 (same op sequence; 16*it+l15 == kb+l15; ascending-k first-min).
    auto kstep = [&](float e2v, float kcol,
                     bf8_t bh0, bf8_t bl0, bf8_t bh1, bf8_t bl1) {
#pragma unroll
        for (int g = 0; g < 2; ++g) {
            f4_t acc = (f4_t){0.f, 0.f, 0.f, 0.f};
            acc = __builtin_amdgcn_mfma_f32_16x16x32_bf16(ah[g][0], bh0, acc, 0, 0, 0);
            acc = __builtin_amdgcn_mfma_f32_16x16x32_bf16(ah[g][0], bl0, acc, 0, 0, 0);
            acc = __builtin_amdgcn_mfma_f32_16x16x32_bf16(al[g][0], bh0, acc, 0, 0, 0);
            acc = __builtin_amdgcn_mfma_f32_16x16x32_bf16(ah[g][1], bh1, acc, 0, 0, 0);
            acc = __builtin_amdgcn_mfma_f32_16x16x32_bf16(ah[g][1], bl1, acc, 0, 0, 0);
            acc = __builtin_amdgcn_mfma_f32_16x16x32_bf16(al[g][1], bh1, acc, 0, 0, 0);
            // D: col=lane&15, row-in-16 = 4q+rg  [m89; R8/R9-validated]
#pragma unroll
            for (int rg = 0; rg < 4; ++rg) {
                const int s = 4 * g + rg;
                float ck = Sv[s] + e2v;                    // np-exact fl(S+e2)
                float u = __builtin_fmaf(-2.0f, acc[rg], ck);
                bool lt = u < v1[s];                       // strict: first-min
                float sp = lt ? v1[s] : u;
                v2[s] = fminf(v2[s], sp);
                kf[s] = lt ? kcol : kf[s];
                v1[s] = fminf(v1[s], u);
            }
        }
    };

    // Flat K-half loop, software-pipelined depth-1 (R15-verbatim structure):
    // wave scans it in [32h, 32h+32). NO barriers. Last prefetch <= 63.
    const int it0 = 32 * h;
    bf8_t cbh0 = *(const bf8_t*)&ehg[1024 * it0 + 8 * lane];
    bf8_t cbh1 = *(const bf8_t*)&ehg[1024 * it0 + 512 + 8 * lane];
    bf8_t cbl0 = *(const bf8_t*)&elg[1024 * it0 + 8 * lane];
    bf8_t cbl1 = *(const bf8_t*)&elg[1024 * it0 + 512 + 8 * lane];
    float ce2 = e2l[16 * it0 + l15];
#pragma unroll 2
    for (int io = 0; io < 31; ++io) {
        const int it = it0 + io;
        const u16* bhp = ehg + 1024 * (it + 1);
        const u16* blp = elg + 1024 * (it + 1);
        bf8_t nbh0 = *(const bf8_t*)&bhp[8 * lane];
        bf8_t nbh1 = *(const bf8_t*)&bhp[512 + 8 * lane];
        bf8_t nbl0 = *(const bf8_t*)&blp[8 * lane];
        bf8_t nbl1 = *(const bf8_t*)&blp[512 + 8 * lane];
        float ne2 = e2l[16 * (it + 1) + l15];
        kstep(ce2, (float)(16 * it + l15), cbh0, cbl0, cbh1, cbl1);
        cbh0 = nbh0; cbh1 = nbh1; cbl0 = nbl0; cbl1 = nbl1; ce2 = ne2;
    }
    kstep(ce2, (float)(16 * (it0 + 31) + l15), cbh0, cbl0, cbh1, cbl1);

    // Merge top-2 across the 16 lanes of each col-class (butterfly, width 16).
#pragma unroll
    for (int m = 1; m < 16; m <<= 1) {
#pragma unroll
        for (int s = 0; s < 8; ++s) {
            float ov1 = __shfl_xor(v1[s], m, 16);
            float okf = __shfl_xor(kf[s], m, 16);
            float ov2 = __shfl_xor(v2[s], m, 16);
            float nmx = fmaxf(v1[s], ov1);
            v2[s] = fminf(fminf(v2[s], ov2), nmx);
            bool lt = ov1 < v1[s];
            kf[s] = lt ? okf : kf[s];
            v1[s] = fminf(v1[s], ov1);
        }
    }

    // Cross-half merge: half-1 publishes; half-0 merges (keeps self on tie --
    // all half-0 k < all half-1 k within a col-class, so first-index holds).
    if (h == 1 && l15 == 0) {
#pragma unroll
        for (int g = 0; g < 2; ++g)
#pragma unroll
            for (int rg = 0; rg < 4; ++rg) {
                const int s = 4 * g + rg;
                const int r = 32 * w4 + 16 * g + 4 * q + rg;
                mv1[r] = v1[s]; mv2[r] = v2[s]; mkf[r] = kf[s];
            }
    }
    __syncthreads();
    if (h == 0 && l15 == 0) {
#pragma unroll
        for (int g = 0; g < 2; ++g)
#pragma unroll
            for (int rg = 0; rg < 4; ++rg) {
                const int s = 4 * g + rg;
                const int r = 32 * w4 + 16 * g + 4 * q + rg;
                float v1b = mv1[r], v2b = mv2[r], kfb = mkf[r];
                float nmx = fmaxf(v1[s], v1b);
                float v2m = fminf(fminf(v2[s], v2b), nmx);
                bool ltb = v1b < v1[s];                    // strict: half-0 on tie
                float kfm = ltb ? kfb : kf[s];
                float v1m = fminf(v1[s], v1b);
                kwin[r] = (int)kfm;
                if (v2m <= v1m + BAND) {    // near-tie (incl. exact ties)
                    int i = atomicAdd(&fbcnt, 1);
                    if (i < FB_MAX) fbrows[i] = r;
                }
            }
    }
    __syncthreads();

    // FALLBACK: np-exact full rescan for near-tie rows (~1%). Uniform skip.
    // LDS-staged (coalesced emb reads, reused across slots) -- R15-verbatim;
    // scalar per-lane emb reads are L2 request-rate poison (R14/R16 lesson).
    const int cnt = min(fbcnt, FB_MAX);
    if (cnt > 0) {
        for (int i = tid; i < cnt * 64; i += NTHR) {
            int fi = i >> 6, l = i & 63;
            xfb[fi * 65 + l] = x[(size_t)b * DD * TT + (size_t)l * TT + t0 + fbrows[fi]];
        }
        u64 pmin[NSL];
#pragma unroll
        for (int sl = 0; sl < NSL; ++sl) pmin[sl] = ~0ull;
#pragma unroll 1
        for (int T2 = 0; T2 < NT; ++T2) {
            __syncthreads();
            {   // stage f32 e tile, stride 65 (chain reads conflict-free)
                const int n = tid >> 3, qd = (tid & 7) * 8;
                const float* sp = emb + (size_t)(T2 * 64 + n) * DD + qd;
                float* dp = efs + n * 65 + qd;
#pragma unroll
                for (int j = 0; j < 8; ++j) dp[j] = sp[j];
            }
            __syncthreads();
#pragma unroll
            for (int sl = 0; sl < NSL; ++sl) {
                const int fi = w + 8 * sl;
                if (fi < cnt) {
                    float acc = 0.0f;
#pragma unroll
                    for (int i = 0; i < 64; ++i)   // np-exact seq-k chain
                        acc = __builtin_fmaf(efs[lane * 65 + i], xfb[fi * 65 + i], acc);
                    float ck = Srow[fbrows[fi]] + e2l[T2 * 64 + lane];
                    float u = __builtin_fmaf(-2.0f, acc, ck);
                    u64 pk = ((u64)flipf(u) << 10) | (unsigned)(T2 * 64 + lane);
                    pmin[sl] = pmin[sl] < pk ? pmin[sl] : pk;
                }
            }
        }
#pragma unroll
        for (int sl = 0; sl < NSL; ++sl) {
            const int fi = w + 8 * sl;
            if (fi < cnt) {
                u64 pk = pmin[sl];
#pragma unroll
                for (int dl = 32; dl > 0; dl >>= 1) {
                    u64 o = __shfl_xor(pk, dl);
                    pk = o < pk ? o : pk;
                }
                if (lane == 0) kwin[fbrows[fi]] = (int)(pk & 1023u);
            }
        }
        __syncthreads();
    }

    // Epilogue: idx, quant_out = emb[kwin] (exact), loss sum.
    if (tid < RPB) out[NELEM + 2 + row0 + tid] = (float)kwin[tid];

    const int r = tid & 127, c0 = (tid >> 7) * 16;
    const int kw = kwin[r];
    const float* eqr = emb + (size_t)kw * DD;
    float lsum = 0.0f;
#pragma unroll 8
    for (int i = 0; i < 16; ++i) {
        const int c = c0 + i;
        const size_t o = (size_t)b * DD * TT + (size_t)c * TT + t0 + r;
        float qv = eqr[c];
        float xv = x[o];
        out[o] = qv;
        float a = qv - xv;
        lsum = __builtin_fmaf(a, a, lsum);
    }
#pragma unroll
    for (int off = 32; off > 0; off >>= 1) lsum += __shfl_down(lsum, off);
    if (lane == 0) atomicAdd(&bsum, lsum);
    __syncthreads();
    if (tid == 0) atomicAdd(ws + WS_LOSS, bsum);
}

__global__ void vq_finalize(const float* __restrict__ ws, float* __restrict__ out) {
    if (threadIdx.x == 0 && blockIdx.x == 0) {
        float M = ws[WS_LOSS] / (float)NELEM;
        out[NELEM + 0] = M;           // codebook_loss
        out[NELEM + 1] = 0.25f * M;   // commitment_loss = BETA * same mean
    }
}

extern "C" void kernel_launch(void* const* d_in, const int* in_sizes, int n_in,
                              void* d_out, int out_size, void* d_ws, size_t ws_size,
                              hipStream_t stream) {
    const float* x = (const float*)d_in[0];
    const float* emb = (const float*)d_in[1];
    float* out = (float*)d_out;
    float* ws = (float*)d_ws;

    vq_prep<<<KCB / 4, 256, 0, stream>>>(emb, ws);
    vq_main<<<BT / RPB, NTHR, 0, stream>>>(x, emb, out, ws);
    vq_finalize<<<1, 64, 0, stream>>>(ws, out);
}

// Round 14
// 186.816 us; speedup vs baseline: 2.9779x; 2.9779x over previous
//
#include <hip/hip_runtime.h>

// VQ-VAE quantizer: x [B=32, C=64, T=4096] f32, emb [K=1024, D=64] f32.
// Outputs flat f32: quant_out [B*C*T], codebook_loss [1], commitment_loss [1],
// idx [B*T] (as float).
//
// CORRECTNESS MODEL (validated R2..R9): checker recomputes the reference with
// numpy f32. d_np(k) = RN( fl(S+e2[k]) - 2*g_k ), g_k = sequential-k single-acc
// FMA chain (BLAS). d~64 -> grid ulp(64)=7.6e-6; near-ties decided by numpy's
// exact rounding. Screen: split-bf16 MFMA (x=xh+xl, e=eh+el; xh*eh + xh*el +
// xl*eh, f32 acc) -> |dot~ - g_k| <= ~1.5e-6. Scan u_k = fl(fl(S+e2[k])-2dot~)
// with np-exact fl(S+e2[k]). Certify winner iff v2-v1 > BAND (4e-5); else
// np-exact full rescan (packed-u64 (flip(d)<<10|k) min = value order +
// first-index tie-break). S,e2: numpy pairwise_sum of fl(v*v), n=64
// (8 accs stride-8, ((r0+r1)+(r2+r3))+((r4+r5)+(r6+r7))).
// DO NOT change fallback chain arithmetic/order or S/e2 pairwise pattern.
//
// R24 = R21 BYTE-IDENTICAL REVERT (best bench 188.7us). R23 (staging
// parallelized 4x + pbuf) passed but hit the codegen cliff: K-loop's
// exactly-full 64-VGPR allocation spilled (FETCH 617MB / WRITE 858MB,
// main ~505us) from an edit OUTSIDE the loop. Same cliff as R13/R19.
// FINAL LEDGER -- refuted levers (busy-times conserved ~21us MFMA /
// ~45us VALU across all 9 structural variants; no pipe >40%):
//   reg pipeline depth 2/3 (R17/R18/R19: scheduler sinks, or pins+spills),
//   LDS-DMA depth (R20), L2 B-traffic cut 4x (R20/R22), wave doubling
//   (R21 ~neutral), barrier cadences (R11/R20/R22), staging parallelism
//   (R14/R23 both regress -- codegen cliff), scalar fallback (R14/R16:
//   uncoalesced per-lane L2 reads = request-rate poison).
// Fixed ~65us of bench total is harness overhead (R16 removed a dispatch,
// total unchanged). Remaining main ~123us = 21 MFMA + 45 VALU busy +
// distributed issue/latency floor at 4-8 waves/SIMD. This is the ceiling
// for this structure on this shape.

typedef unsigned long long u64;
typedef unsigned short u16;
typedef __attribute__((ext_vector_type(8))) short bf8_t;   // 8 bf16 (A/B frag)
typedef __attribute__((ext_vector_type(4))) float f4_t;    // 4 f32  (C/D frag)

#define KCB 1024
#define DD 64
#define BB 32
#define TT 4096
#define BT (BB * TT)
#define NELEM (BB * DD * TT)

#define RPB 128                // rows per block
#define NTHR 512               // 8 waves: 4 row-pair owners x 2 K-halves
#define NT 16                  // emb tiles (64 cands each)
#define FB_MAX 48
#define NSL 6                  // FB slots per wave: 8 waves * 6 = 48
#define BAND 4e-5f

#define WS_LOSS 0
#define WS_E2 64
#define WS_EH 2048             // float offset: eh frag table (64Ki u16 = 128KB)
#define WS_EL 34816            // el frag table

static __device__ __forceinline__ u16 bf16rte(float f) {
    unsigned u = __float_as_uint(f);
    return (u16)((u + 0x7FFFu + ((u >> 16) & 1u)) >> 16);
}
static __device__ __forceinline__ unsigned flipf(float f) {
    unsigned u = __float_as_uint(f);
    return (u & 0x80000000u) ? ~u : (u | 0x80000000u);
}
// frag-order index within a 64-cand tile: cand n, dim d -> u16 index
static __device__ __forceinline__ int fragidx(int n, int d) {
    return 1024 * (n >> 4) + 512 * (d >> 5) + 128 * ((d >> 3) & 3)
         + 8 * (n & 15) + (d & 7);
}

// Prep: parallel (256 blocks x 256 thr; block owns 4 cands). np-exact e2 via
// LDS pairwise; split-bf16 frag-order tables; coalesced loads. UNCHANGED.
__global__ void vq_prep(const float* __restrict__ emb, float* __restrict__ ws) {
#pragma clang fp contract(off)
    const int tid = threadIdx.x;
    const int kl = tid >> 6, d = tid & 63;
    const int k = blockIdx.x * 4 + kl;
    if (blockIdx.x == 0 && tid == 0) ws[WS_LOSS] = 0.0f;
    __shared__ float sq[4][64];
    __shared__ float rsh[4][8];
    float v = emb[(size_t)k * DD + d];
    u16 hb = bf16rte(v);
    float hv = __uint_as_float((unsigned)hb << 16);
    u16 lb = bf16rte(v - hv);                  // v-hv exact (Sterbenz)
    u16* ehg = (u16*)(ws + WS_EH) + 4096 * (k >> 6);
    u16* elg = (u16*)(ws + WS_EL) + 4096 * (k >> 6);
    const int ia = fragidx(k & 63, d);
    ehg[ia] = hb; elg[ia] = lb;
    sq[kl][d] = v * v;                         // fl(e*e) individually rounded
    __syncthreads();
    if (tid < 32) {
        const int g = tid >> 3, j = tid & 7;
        float r = sq[g][j];
#pragma unroll
        for (int i = 1; i < 8; ++i) r += sq[g][8 * i + j];   // i ascending
        rsh[g][j] = r;
    }
    __syncthreads();
    if (tid < 4) {
        const float* r = rsh[tid];
        ws[WS_E2 + blockIdx.x * 4 + tid] =
            ((r[0] + r[1]) + (r[2] + r[3])) + ((r[4] + r[5]) + (r[6] + r[7]));
    }
}

__launch_bounds__(NTHR, 4)
__global__ void vq_main(const float* __restrict__ x, const float* __restrict__ emb,
                        float* __restrict__ out, float* __restrict__ ws) {
#pragma clang fp contract(off)
    const int tid = threadIdx.x;
    const int lane = tid & 63;
    const int w = __builtin_amdgcn_readfirstlane(tid >> 6);   // 0..7
    const int w4 = w & 3;                       // row-pair owner
    const int h = w >> 2;                       // K-half: 0 -> it 0..31, 1 -> 32..63
    const int l15 = lane & 15, q = lane >> 4;

    const int row0 = blockIdx.x * RPB;          // 128 | 4096 -> b uniform
    const int b = row0 >> 12;
    const int t0 = row0 & (TT - 1);

    // Arena: [stage] xhT 16K + xlT 16K -> [merge] mv1/mv2/mkf (1.5KB) ->
    // [fallback] efs (16640B) + xfb (48x65 f32). Lifetimes barrier-separated.
    __shared__ __align__(16) char arena[32768];
    u16* xhT = (u16*)arena;
    u16* xlT = (u16*)(arena + 16384);
    float* mv1 = (float*)arena;                 // [128] half-1 v1
    float* mv2 = (float*)(arena + 512);         // [128] half-1 v2
    float* mkf = (float*)(arena + 1024);        // [128] half-1 kf
    float* efs = (float*)arena;
    float* xfb = (float*)(arena + 16640);

    __shared__ float e2l[KCB];                  // np-exact e2, 4KB
    __shared__ float Srow[RPB];
    __shared__ int kwin[RPB];
    __shared__ int fbrows[FB_MAX];
    __shared__ int fbcnt;
    __shared__ float bsum;

    if (tid == 0) { fbcnt = 0; bsum = 0.0f; }
#pragma unroll
    for (int i = tid; i < KCB; i += NTHR) e2l[i] = ws[WS_E2 + i];

    // x stage: thread r<128 owns a row -- np-exact S + split-bf16 frag writes.
    // (champion-verbatim; waves 2-7 wait at the barrier)
    if (tid < RPB) {
        const int r = tid;
        const float* xr = x + (size_t)b * DD * TT + t0 + r;
        const int gb = 1024 * (r >> 4);
        float rr[8];
#pragma unroll
        for (int i = 0; i < 64; i += 8) {
#pragma unroll
            for (int j = 0; j < 8; ++j) {
                float v = xr[(size_t)(i + j) * TT];
                if (i == 0) rr[j] = v * v; else rr[j] += v * v;
                u16 hb = bf16rte(v);
                float hv = __uint_as_float((unsigned)hb << 16);
                u16 lb = bf16rte(v - hv);
                const int ia = gb + fragidx(r & 15, i + j);
                xhT[ia] = hb; xlT[ia] = lb;
            }
        }
        Srow[r] = ((rr[0] + rr[1]) + (rr[2] + rr[3])) + ((rr[4] + rr[5]) + (rr[6] + rr[7]));
    }
    __syncthreads();

    // A-frags: wave w owns row-groups 2*w4, 2*w4+1 (32 rows); loaded once
    // as whole bf8_t (ds_read_b128 -- codegen invariant, R13 lesson).
    bf8_t ah[2][2], al[2][2];
#pragma unroll
    for (int g = 0; g < 2; ++g) {
        const int gg = 2 * w4 + g;
        ah[g][0] = *(const bf8_t*)&xhT[1024 * gg + 8 * lane];
        ah[g][1] = *(const bf8_t*)&xhT[1024 * gg + 512 + 8 * lane];
        al[g][0] = *(const bf8_t*)&xlT[1024 * gg + 8 * lane];
        al[g][1] = *(const bf8_t*)&xlT[1024 * gg + 512 + 8 * lane];
    }
    float Sv[8];
#pragma unroll
    for (int g = 0; g < 2; ++g)
#pragma unroll
        for (int rg = 0; rg < 4; ++rg)
            Sv[4 * g + rg] = Srow[32 * w4 + 16 * g + 4 * q + rg];
    __syncthreads();                           // arena officially dead for all

    // In-register scan state: thread owns 8 rows (4q+rg in each group), cols
    // congruent to l15 (mod 16). All indices compile-time after unroll.
    float v1[8], v2[8], kf[8];
#pragma unroll
    for (int s = 0; s < 8; ++s) { v1[s] = 3.4e38f; v2[s] = 3.4e38f; kf[s] = 0.0f; }

    const u16* ehg = (const u16*)(ws + WS_EH);
    const u16* elg = (const u16*)(ws + WS_EL);

    // One K-step: 12 MFMA + scan for 16 candidates. Arithmetic identical to
    // R10/R15 (same op sequence; 16*it+l15 == kb+l15; ascending-k first-min).
    auto kstep = [&](float e2v, float kcol,
                     bf8_t bh0, bf8_t bl0, bf8_t bh1, bf8_t bl1) {
#pragma unroll
        for (int g = 0; g < 2; ++g) {
            f4_t acc = (f4_t){0.f, 0.f, 0.f, 0.f};
            acc = __builtin_amdgcn_mfma_f32_16x16x32_bf16(ah[g][0], bh0, acc, 0, 0, 0);
            acc = __builtin_amdgcn_mfma_f32_16x16x32_bf16(ah[g][0], bl0, acc, 0, 0, 0);
            acc = __builtin_amdgcn_mfma_f32_16x16x32_bf16(al[g][0], bh0, acc, 0, 0, 0);
            acc = __builtin_amdgcn_mfma_f32_16x16x32_bf16(ah[g][1], bh1, acc, 0, 0, 0);
            acc = __builtin_amdgcn_mfma_f32_16x16x32_bf16(ah[g][1], bl1, acc, 0, 0, 0);
            acc = __builtin_amdgcn_mfma_f32_16x16x32_bf16(al[g][1], bh1, acc, 0, 0, 0);
            // D: col=lane&15, row-in-16 = 4q+rg  [m89; R8/R9-validated]
#pragma unroll
            for (int rg = 0; rg < 4; ++rg) {
                const int s = 4 * g + rg;
                float ck = Sv[s] + e2v;                    // np-exact fl(S+e2)
                float u = __builtin_fmaf(-2.0f, acc[rg], ck);
                bool lt = u < v1[s];                       // strict: first-min
                float sp = lt ? v1[s] : u;
                v2[s] = fminf(v2[s], sp);
                kf[s] = lt ? kcol : kf[s];
                v1[s] = fminf(v1[s], u);
            }
        }
    };

    // Flat K-half loop, software-pipelined depth-1 (R15-verbatim structure):
    // wave scans it in [32h, 32h+32). NO barriers. Last prefetch <= 63.
    const int it0 = 32 * h;
    bf8_t cbh0 = *(const bf8_t*)&ehg[1024 * it0 + 8 * lane];
    bf8_t cbh1 = *(const bf8_t*)&ehg[1024 * it0 + 512 + 8 * lane];
    bf8_t cbl0 = *(const bf8_t*)&elg[1024 * it0 + 8 * lane];
    bf8_t cbl1 = *(const bf8_t*)&elg[1024 * it0 + 512 + 8 * lane];
    float ce2 = e2l[16 * it0 + l15];
#pragma unroll 2
    for (int io = 0; io < 31; ++io) {
        const int it = it0 + io;
        const u16* bhp = ehg + 1024 * (it + 1);
        const u16* blp = elg + 1024 * (it + 1);
        bf8_t nbh0 = *(const bf8_t*)&bhp[8 * lane];
        bf8_t nbh1 = *(const bf8_t*)&bhp[512 + 8 * lane];
        bf8_t nbl0 = *(const bf8_t*)&blp[8 * lane];
        bf8_t nbl1 = *(const bf8_t*)&blp[512 + 8 * lane];
        float ne2 = e2l[16 * (it + 1) + l15];
        kstep(ce2, (float)(16 * it + l15), cbh0, cbl0, cbh1, cbl1);
        cbh0 = nbh0; cbh1 = nbh1; cbl0 = nbl0; cbl1 = nbl1; ce2 = ne2;
    }
    kstep(ce2, (float)(16 * (it0 + 31) + l15), cbh0, cbl0, cbh1, cbl1);

    // Merge top-2 across the 16 lanes of each col-class (butterfly, width 16).
#pragma unroll
    for (int m = 1; m < 16; m <<= 1) {
#pragma unroll
        for (int s = 0; s < 8; ++s) {
            float ov1 = __shfl_xor(v1[s], m, 16);
            float okf = __shfl_xor(kf[s], m, 16);
            float ov2 = __shfl_xor(v2[s], m, 16);
            float nmx = fmaxf(v1[s], ov1);
            v2[s] = fminf(fminf(v2[s], ov2), nmx);
            bool lt = ov1 < v1[s];
            kf[s] = lt ? okf : kf[s];
            v1[s] = fminf(v1[s], ov1);
        }
    }

    // Cross-half merge: half-1 publishes; half-0 merges (keeps self on tie --
    // all half-0 k < all half-1 k within a col-class, so first-index holds).
    if (h == 1 && l15 == 0) {
#pragma unroll
        for (int g = 0; g < 2; ++g)
#pragma unroll
            for (int rg = 0; rg < 4; ++rg) {
                const int s = 4 * g + rg;
                const int r = 32 * w4 + 16 * g + 4 * q + rg;
                mv1[r] = v1[s]; mv2[r] = v2[s]; mkf[r] = kf[s];
            }
    }
    __syncthreads();
    if (h == 0 && l15 == 0) {
#pragma unroll
        for (int g = 0; g < 2; ++g)
#pragma unroll
            for (int rg = 0; rg < 4; ++rg) {
                const int s = 4 * g + rg;
                const int r = 32 * w4 + 16 * g + 4 * q + rg;
                float v1b = mv1[r], v2b = mv2[r], kfb = mkf[r];
                float nmx = fmaxf(v1[s], v1b);
                float v2m = fminf(fminf(v2[s], v2b), nmx);
                bool ltb = v1b < v1[s];                    // strict: half-0 on tie
                float kfm = ltb ? kfb : kf[s];
                float v1m = fminf(v1[s], v1b);
                kwin[r] = (int)kfm;
                if (v2m <= v1m + BAND) {    // near-tie (incl. exact ties)
                    int i = atomicAdd(&fbcnt, 1);
                    if (i < FB_MAX) fbrows[i] = r;
                }
            }
    }
    __syncthreads();

    // FALLBACK: np-exact full rescan for near-tie rows (~1%). Uniform skip.
    // LDS-staged (coalesced emb reads, reused across slots) -- R15-verbatim;
    // scalar per-lane emb reads are L2 request-rate poison (R14/R16 lesson).
    const int cnt = min(fbcnt, FB_MAX);
    if (cnt > 0) {
        for (int i = tid; i < cnt * 64; i += NTHR) {
            int fi = i >> 6, l = i & 63;
            xfb[fi * 65 + l] = x[(size_t)b * DD * TT + (size_t)l * TT + t0 + fbrows[fi]];
        }
        u64 pmin[NSL];
#pragma unroll
        for (int sl = 0; sl < NSL; ++sl) pmin[sl] = ~0ull;
#pragma unroll 1
        for (int T2 = 0; T2 < NT; ++T2) {
            __syncthreads();
            {   // stage f32 e tile, stride 65 (chain reads conflict-free)
                const int n = tid >> 3, qd = (tid & 7) * 8;
                const float* sp = emb + (size_t)(T2 * 64 + n) * DD + qd;
                float* dp = efs + n * 65 + qd;
#pragma unroll
                for (int j = 0; j < 8; ++j) dp[j] = sp[j];
            }
            __syncthreads();
#pragma unroll
            for (int sl = 0; sl < NSL; ++sl) {
                const int fi = w + 8 * sl;
                if (fi < cnt) {
                    float acc = 0.0f;
#pragma unroll
                    for (int i = 0; i < 64; ++i)   // np-exact seq-k chain
                        acc = __builtin_fmaf(efs[lane * 65 + i], xfb[fi * 65 + i], acc);
                    float ck = Srow[fbrows[fi]] + e2l[T2 * 64 + lane];
                    float u = __builtin_fmaf(-2.0f, acc, ck);
                    u64 pk = ((u64)flipf(u) << 10) | (unsigned)(T2 * 64 + lane);
                    pmin[sl] = pmin[sl] < pk ? pmin[sl] : pk;
                }
            }
        }
#pragma unroll
        for (int sl = 0; sl < NSL; ++sl) {
            const int fi = w + 8 * sl;
            if (fi < cnt) {
                u64 pk = pmin[sl];
#pragma unroll
                for (int dl = 32; dl > 0; dl >>= 1) {
                    u64 o = __shfl_xor(pk, dl);
                    pk = o < pk ? o : pk;
                }
                if (lane == 0) kwin[fbrows[fi]] = (int)(pk & 1023u);
            }
        }
        __syncthreads();
    }

    // Epilogue: idx, quant_out = emb[kwin] (exact), loss sum.
    if (tid < RPB) out[NELEM + 2 + row0 + tid] = (float)kwin[tid];

    const int r = tid & 127, c0 = (tid >> 7) * 16;
    const int kw = kwin[r];
    const float* eqr = emb + (size_t)kw * DD;
    float lsum = 0.0f;
#pragma unroll 8
    for (int i = 0; i < 16; ++i) {
        const int c = c0 + i;
        const size_t o = (size_t)b * DD * TT + (size_t)c * TT + t0 + r;
        float qv = eqr[c];
        float xv = x[o];
        out[o] = qv;
        float a = qv - xv;
        lsum = __builtin_fmaf(a, a, lsum);
    }
#pragma unroll
    for (int off = 32; off > 0; off >>= 1) lsum += __shfl_down(lsum, off);
    if (lane == 0) atomicAdd(&bsum, lsum);
    __syncthreads();
    if (tid == 0) atomicAdd(ws + WS_LOSS, bsum);
}

__global__ void vq_finalize(const float* __restrict__ ws, float* __restrict__ out) {
    if (threadIdx.x == 0 && blockIdx.x == 0) {
        float M = ws[WS_LOSS] / (float)NELEM;
        out[NELEM + 0] = M;           // codebook_loss
        out[NELEM + 1] = 0.25f * M;   // commitment_loss = BETA * same mean
    }
}

extern "C" void kernel_launch(void* const* d_in, const int* in_sizes, int n_in,
                              void* d_out, int out_size, void* d_ws, size_t ws_size,
                              hipStream_t stream) {
    const float* x = (const float*)d_in[0];
    const float* emb = (const float*)d_in[1];
    float* out = (float*)d_out;
    float* ws = (float*)d_ws;

    vq_prep<<<KCB / 4, 256, 0, stream>>>(emb, ws);
    vq_main<<<BT / RPB, NTHR, 0, stream>>>(x, emb, out, ws);
    vq_finalize<<<1, 64, 0, stream>>>(ws, out);
}